// Round 4
// baseline (857.847 us; speedup 1.0000x reference)
//
#include <hip/hip_runtime.h>
#include <hip/hip_bf16.h>
#include <stdint.h>

typedef __attribute__((ext_vector_type(8))) __bf16 bf16x8;
typedef __attribute__((ext_vector_type(4))) float floatx4;

__device__ __forceinline__ unsigned short f2bf(float f) {
  __hip_bfloat16 h = __float2bfloat16(f);
  return __builtin_bit_cast(unsigned short, h);
}
__device__ __forceinline__ __bf16 f2b(float f) {
  return __builtin_bit_cast(__bf16, f2bf(f));
}
// load 8 consecutive floats, convert to bf16x8 (RNE)
__device__ __forceinline__ bf16x8 cvt8(const float* p) {
  floatx4 a = *(const floatx4*)p;
  floatx4 b = *(const floatx4*)(p + 4);
  bf16x8 r;
#pragma unroll
  for (int i = 0; i < 4; ++i) {
    r[i] = f2b(a[i]);
    r[4 + i] = f2b(b[i]);
  }
  return r;
}
__device__ __forceinline__ int reg3(int t) { return t < 49 ? 0 : (t < 53 ? 1 : 2); }

// LDS element offsets (unsigned short units)
#define XW 0        // [49][392]  gathered window (bf16, padded stride)
#define QO 19208    // [64][40]
#define KO 21768    // [64][40]
#define VT 24328    // [32][72]   v transposed: row=d, col=token
#define PO 19208    // [64][72]   aliases QO/KO (dead by then)
#define LDSN 26632  // 53,264 bytes

// ---------------------------------------------------------------------------
// Kernel 1: fused shift-gather + QKV + windowed attention (fp32 I/O).
// One block per window; O (pre-proj) written fp32 to `out` at the
// inverse-shifted spatial location; proj then runs in-place.
// ---------------------------------------------------------------------------
__global__ __launch_bounds__(256) void swin_fused(
    const float* __restrict__ x,
    const float* __restrict__ w,
    const float* __restrict__ qkvb,
    const float* __restrict__ table,
    float* __restrict__ out) {
  __shared__ unsigned short lds[LDSN];
  const int tid = threadIdx.x;
  const int wave = tid >> 6, lane = tid & 63, quad = lane >> 4, l16 = lane & 15;
  const int bw = blockIdx.x;  // 0..1023
  const int b = bw >> 6, win = bw & 63, wy = win >> 3, wx = win & 7;

  bf16x8 zf;
#pragma unroll
  for (int i = 0; i < 8; ++i) zf[i] = (__bf16)0.0f;
  const floatx4 zz = {0.f, 0.f, 0.f, 0.f};

  // Phase A: gather shifted window rows into LDS (rows 0..48), fp32 -> bf16.
  for (int c = tid; c < 2352; c += 256) {
    int r = c / 48, c8 = c - r * 48;
    int py = (r * 37) >> 8, px = r - py * 7;
    int hh = wy * 7 + py + 3; if (hh >= 56) hh -= 56;
    int wc = wx * 7 + px + 3; if (wc >= 56) wc -= 56;
    *(bf16x8*)&lds[XW + r * 392 + c8 * 8] =
        cvt8(x + (size_t)((b * 56 + hh) * 56 + wc) * 384 + c8 * 8);
  }
  __syncthreads();

  // Column-side mask precompute (head-independent).
  int yj[4], xj[4], ccv[4];
#pragma unroll
  for (int nt = 0; nt < 4; ++nt) {
    int j = nt * 16 + l16;
    int y = (j * 37) >> 8, xx = j - y * 7;
    yj[nt] = y; xj[nt] = xx;
    ccv[nt] = reg3(wy * 7 + y) * 3 + reg3(wx * 7 + xx);
  }

  for (int g = 0; g < 3; ++g) {
    const int hme = g * 4 + wave;  // head this wave's GEMM columns belong to
    const float* bp[6];
    int wrowv[6];
#pragma unroll
    for (int nt = 0; nt < 6; ++nt) {
      int which = nt >> 1;             // 0:q 1:k 2:v
      int n32 = (nt & 1) * 16 + l16;   // 0..31 within head
      int wrow = which * 384 + hme * 32 + n32;
      wrowv[nt] = wrow;
      bp[nt] = w + (size_t)wrow * 384 + quad * 8;
    }

    floatx4 acc[4][6];
#pragma unroll
    for (int mt = 0; mt < 4; ++mt)
#pragma unroll
      for (int nt = 0; nt < 6; ++nt) acc[mt][nt] = zz;

    // QKV GEMM for this wave's head: C[64 x 96], K=384.
    for (int ks = 0; ks < 12; ++ks) {
      bf16x8 af[4];
#pragma unroll
      for (int mt = 0; mt < 4; ++mt) {
        int am = mt * 16 + l16;
        af[mt] = (am < 49) ? *(const bf16x8*)&lds[XW + am * 392 + ks * 32 + quad * 8] : zf;
      }
#pragma unroll
      for (int nt = 0; nt < 6; ++nt) {
        bf16x8 bfr = cvt8(bp[nt] + ks * 32);
#pragma unroll
        for (int mt = 0; mt < 4; ++mt)
          acc[mt][nt] = __builtin_amdgcn_mfma_f32_16x16x32_bf16(af[mt], bfr, acc[mt][nt], 0, 0, 0);
      }
    }

    // Per-head attention.
    for (int hh2 = 0; hh2 < 4; ++hh2) {
      const int h = g * 4 + hh2;
      __syncthreads();  // (a) prior P/vT reads complete before overwrite
      if (wave == hh2) {
        float bb[6];
#pragma unroll
        for (int nt = 0; nt < 6; ++nt) bb[nt] = qkvb[wrowv[nt]];
#pragma unroll
        for (int mt = 0; mt < 4; ++mt) {
#pragma unroll
          for (int r = 0; r < 4; ++r) {
            int token = mt * 16 + quad * 4 + r;
#pragma unroll
            for (int nt = 0; nt < 6; ++nt) {
              float val = acc[mt][nt][r] + bb[nt];
              int n32 = (nt & 1) * 16 + l16;
              if (nt < 2)
                lds[QO + token * 40 + n32] = f2bf(val * 0.17677669529663687f);
              else if (nt < 4)
                lds[KO + token * 40 + n32] = f2bf(val);
              else
                lds[VT + n32 * 72 + token] = f2bf(val);
            }
          }
        }
      }
      __syncthreads();  // (b) q/k/vT visible

      bf16x8 aq = *(const bf16x8*)&lds[QO + (wave * 16 + l16) * 40 + quad * 8];
      bf16x8 bk[4];
#pragma unroll
      for (int nt = 0; nt < 4; ++nt)
        bk[nt] = *(const bf16x8*)&lds[KO + (nt * 16 + l16) * 40 + quad * 8];
      bf16x8 bv[2][2];
#pragma unroll
      for (int nt = 0; nt < 2; ++nt)
#pragma unroll
        for (int ks = 0; ks < 2; ++ks)
          bv[nt][ks] = *(const bf16x8*)&lds[VT + (nt * 16 + l16) * 72 + ks * 32 + quad * 8];
      __syncthreads();  // (c) frags in regs before P overwrites q/k

      floatx4 s4[4];
#pragma unroll
      for (int nt = 0; nt < 4; ++nt)
        s4[nt] = __builtin_amdgcn_mfma_f32_16x16x32_bf16(aq, bk[nt], zz, 0, 0, 0);

      const float NEG = -1e30f;
#pragma unroll
      for (int r = 0; r < 4; ++r) {
        int i = wave * 16 + quad * 4 + r;
        int yi = (i * 37) >> 8, xi = i - yi * 7;
        int rc = reg3(wy * 7 + yi) * 3 + reg3(wx * 7 + xi);
        bool rowok = (i < 49);
        float vals[4];
        float mx = NEG;
#pragma unroll
        for (int nt = 0; nt < 4; ++nt) {
          int j = nt * 16 + l16;
          float v = s4[nt][r];
          if (rowok && j < 49) {
            v += table[((yi - yj[nt] + 6) * 13 + (xi - xj[nt] + 6)) * 12 + h];
            if (rc != ccv[nt]) v -= 100.0f;
          } else {
            v = NEG;
          }
          vals[nt] = v;
          mx = fmaxf(mx, v);
        }
#pragma unroll
        for (int off = 1; off < 16; off <<= 1)
          mx = fmaxf(mx, __shfl_xor(mx, off, 64));
        float sum = 0.f;
#pragma unroll
        for (int nt = 0; nt < 4; ++nt) {
          float e = __expf(vals[nt] - mx);
          vals[nt] = e;
          sum += e;
        }
#pragma unroll
        for (int off = 1; off < 16; off <<= 1) sum += __shfl_xor(sum, off, 64);
        float rinv = 1.f / sum;
#pragma unroll
        for (int nt = 0; nt < 4; ++nt)
          lds[PO + i * 72 + nt * 16 + l16] = f2bf(vals[nt] * rinv);
      }
      __syncthreads();  // (d) P visible

      bf16x8 ap[2];
#pragma unroll
      for (int ks = 0; ks < 2; ++ks)
        ap[ks] = *(const bf16x8*)&lds[PO + (wave * 16 + l16) * 72 + ks * 32 + quad * 8];
      floatx4 o2[2] = {zz, zz};
#pragma unroll
      for (int ks = 0; ks < 2; ++ks)
#pragma unroll
        for (int nt = 0; nt < 2; ++nt)
          o2[nt] = __builtin_amdgcn_mfma_f32_16x16x32_bf16(ap[ks], bv[nt][ks], o2[nt], 0, 0, 0);

#pragma unroll
      for (int r = 0; r < 4; ++r) {
        int i = wave * 16 + quad * 4 + r;
        if (i < 49) {
          int py = (i * 37) >> 8, px = i - py * 7;
          int hh = wy * 7 + py + 3; if (hh >= 56) hh -= 56;
          int wc = wx * 7 + px + 3; if (wc >= 56) wc -= 56;
          size_t base = (size_t)((b * 56 + hh) * 56 + wc) * 384 + h * 32;
#pragma unroll
          for (int nt = 0; nt < 2; ++nt)
            out[base + nt * 16 + l16] = o2[nt][r];
        }
      }
    }
  }
}

// ---------------------------------------------------------------------------
// Kernel 2: in-place proj GEMM (fp32 I/O). Each block owns 64 complete rows
// of `out`, loads them fully into LDS (as bf16) before writing back.
// ---------------------------------------------------------------------------
__global__ __launch_bounds__(256) void proj_inplace(
    float* __restrict__ out,
    const float* __restrict__ w,
    const float* __restrict__ pb) {
  __shared__ unsigned short A[64 * 392];  // 50,176 B
  const int tid = threadIdx.x;
  const int wave = tid >> 6, lane = tid & 63, quad = lane >> 4, l16 = lane & 15;
  const int tm = blockIdx.x;  // 0..783

  for (int c = tid; c < 3072; c += 256) {
    int r = c / 48, c8 = c - r * 48;
    *(bf16x8*)&A[r * 392 + c8 * 8] =
        cvt8(out + (size_t)(tm * 64 + r) * 384 + c8 * 8);
  }
  __syncthreads();

  const float* bp[6];
#pragma unroll
  for (int nt = 0; nt < 6; ++nt)
    bp[nt] = w + (size_t)(wave * 96 + nt * 16 + l16) * 384 + quad * 8;

  const floatx4 zz = {0.f, 0.f, 0.f, 0.f};
  floatx4 acc[4][6];
#pragma unroll
  for (int mt = 0; mt < 4; ++mt)
#pragma unroll
    for (int nt = 0; nt < 6; ++nt) acc[mt][nt] = zz;

  for (int ks = 0; ks < 12; ++ks) {
    bf16x8 af[4];
#pragma unroll
    for (int mt = 0; mt < 4; ++mt)
      af[mt] = *(const bf16x8*)&A[(mt * 16 + l16) * 392 + ks * 32 + quad * 8];
#pragma unroll
    for (int nt = 0; nt < 6; ++nt) {
      bf16x8 bfr = cvt8(bp[nt] + ks * 32);
#pragma unroll
      for (int mt = 0; mt < 4; ++mt)
        acc[mt][nt] = __builtin_amdgcn_mfma_f32_16x16x32_bf16(af[mt], bfr, acc[mt][nt], 0, 0, 0);
    }
  }

#pragma unroll
  for (int mt = 0; mt < 4; ++mt) {
#pragma unroll
    for (int r = 0; r < 4; ++r) {
      int t = tm * 64 + mt * 16 + quad * 4 + r;
#pragma unroll
      for (int nt = 0; nt < 6; ++nt) {
        int col = wave * 96 + nt * 16 + l16;
        out[(size_t)t * 384 + col] = acc[mt][nt][r] + pb[col];
      }
    }
  }
}

extern "C" void kernel_launch(void* const* d_in, const int* in_sizes, int n_in,
                              void* d_out, int out_size, void* d_ws, size_t ws_size,
                              hipStream_t stream) {
  const float* x      = (const float*)d_in[0];
  const float* qkv_w  = (const float*)d_in[1];
  const float* qkv_b  = (const float*)d_in[2];
  const float* proj_w = (const float*)d_in[3];
  const float* proj_b = (const float*)d_in[4];
  const float* table  = (const float*)d_in[5];
  float* out = (float*)d_out;

  // Zero-workspace pipeline: attention output lives in d_out, proj is in-place.
  swin_fused<<<1024, 256, 0, stream>>>(x, qkv_w, qkv_b, table, out);
  proj_inplace<<<784, 256, 0, stream>>>(out, proj_w, proj_b);
}

// Round 5
// 298.230 us; speedup vs baseline: 2.8765x; 2.8765x over previous
//
#include <hip/hip_runtime.h>
#include <hip/hip_bf16.h>
#include <stdint.h>

typedef __attribute__((ext_vector_type(8))) __bf16 bf16x8;
typedef __attribute__((ext_vector_type(4))) float floatx4;

__device__ __forceinline__ unsigned short f2bf(float f) {
  __hip_bfloat16 h = __float2bfloat16(f);
  return __builtin_bit_cast(unsigned short, h);
}
__device__ __forceinline__ __bf16 f2b(float f) {
  return __builtin_bit_cast(__bf16, f2bf(f));
}
__device__ __forceinline__ float bf2f(unsigned short u) {
  __hip_bfloat16 h = __builtin_bit_cast(__hip_bfloat16, u);
  return __bfloat162float(h);
}
__device__ __forceinline__ bf16x8 cvt8(const float* p) {
  floatx4 a = *(const floatx4*)p;
  floatx4 b = *(const floatx4*)(p + 4);
  bf16x8 r;
#pragma unroll
  for (int i = 0; i < 4; ++i) { r[i] = f2b(a[i]); r[4 + i] = f2b(b[i]); }
  return r;
}
__device__ __forceinline__ void gload_lds16(const unsigned short* g, unsigned short* l) {
  __builtin_amdgcn_global_load_lds(
      (const __attribute__((address_space(1))) unsigned int*)g,
      (__attribute__((address_space(3))) unsigned int*)l, 16, 0, 0);
}
__device__ __forceinline__ int reg3(int t) { return t < 49 ? 0 : (t < 53 ? 1 : 2); }

#define NX 19267584
#define NQW 442368
#define NPW 147456

// ---------------------------------------------------------------------------
// Kernel 0: fp32 -> bf16 conversion of x, qkv_w, proj_w into ws.
// ---------------------------------------------------------------------------
__global__ __launch_bounds__(256) void cvt_all(
    const float* __restrict__ x, const float* __restrict__ wq,
    const float* __restrict__ wp, unsigned short* __restrict__ xb,
    unsigned short* __restrict__ wqb, unsigned short* __restrict__ wpb) {
  int i = (blockIdx.x * 256 + threadIdx.x) * 8;
  if (i < NX) {
    *(bf16x8*)(xb + i) = cvt8(x + i);
  } else if (i < NX + NQW) {
    int o = i - NX;
    *(bf16x8*)(wqb + o) = cvt8(wq + o);
  } else {
    int o = i - NX - NQW;
    *(bf16x8*)(wpb + o) = cvt8(wp + o);
  }
}

// ---------------------------------------------------------------------------
// Kernel 1: fused shift-gather + QKV GEMM (bf16 in/out).
// q (scaled) and k -> qk rows [50176][768] (in d_out); v -> vb [50176][384].
// ---------------------------------------------------------------------------
__global__ __launch_bounds__(256, 2) void qkv_gemm(
    const unsigned short* __restrict__ xb,
    const unsigned short* __restrict__ w,
    const float* __restrict__ bias,
    unsigned short* __restrict__ qk,
    unsigned short* __restrict__ vb) {
  __shared__ unsigned short As[128 * 32];
  __shared__ unsigned short Bs[128 * 32];
  const int tid = threadIdx.x;
  const int wave = tid >> 6, lane = tid & 63, quad = lane >> 4, l16 = lane & 15;
  const int tm = blockIdx.x;  // 0..391
  const int tn = blockIdx.y;  // 0..8

  const unsigned short* asrc[2];
  const unsigned short* bsrc[2];
#pragma unroll
  for (int s = 0; s < 2; ++s) {
    int row = wave * 32 + s * 16 + (lane >> 2);
    int t = tm * 128 + row;
    int bw = t / 49;
    int pos = t - bw * 49;
    int b = bw >> 6, win = bw & 63, wy = win >> 3, wx = win & 7;
    int py = pos / 7, px = pos - py * 7;
    int hh = wy * 7 + py + 3; if (hh >= 56) hh -= 56;
    int wc = wx * 7 + px + 3; if (wc >= 56) wc -= 56;
    asrc[s] = xb + (size_t)((b * 56 + hh) * 56 + wc) * 384 + (lane & 3) * 8;
    bsrc[s] = w + (size_t)(tn * 128 + row) * 384 + (lane & 3) * 8;
  }

  const int wm = (wave & 1) * 64, wn = (wave >> 1) * 64;
  const floatx4 zz = {0.f, 0.f, 0.f, 0.f};
  floatx4 acc[4][4];
#pragma unroll
  for (int i = 0; i < 4; ++i)
#pragma unroll
    for (int j = 0; j < 4; ++j) acc[i][j] = zz;

  for (int kk = 0; kk < 12; ++kk) {
    if (kk) __syncthreads();
#pragma unroll
    for (int s = 0; s < 2; ++s) {
      gload_lds16(asrc[s] + kk * 32, &As[(wave * 32 + s * 16) * 32]);
      gload_lds16(bsrc[s] + kk * 32, &Bs[(wave * 32 + s * 16) * 32]);
    }
    __syncthreads();
    bf16x8 af[4], bfg[4];
#pragma unroll
    for (int i = 0; i < 4; ++i) {
      af[i]  = *(const bf16x8*)&As[(wm + i * 16 + l16) * 32 + quad * 8];
      bfg[i] = *(const bf16x8*)&Bs[(wn + i * 16 + l16) * 32 + quad * 8];
    }
#pragma unroll
    for (int i = 0; i < 4; ++i)
#pragma unroll
      for (int j = 0; j < 4; ++j)
        acc[i][j] = __builtin_amdgcn_mfma_f32_16x16x32_bf16(af[i], bfg[j], acc[i][j], 0, 0, 0);
  }

  float bb[4];
  int ov[4];
#pragma unroll
  for (int j = 0; j < 4; ++j) {
    ov[j] = tn * 128 + wn + j * 16 + l16;
    bb[j] = bias[ov[j]];
  }

#pragma unroll
  for (int i = 0; i < 4; ++i) {
#pragma unroll
    for (int r = 0; r < 4; ++r) {
      int t = tm * 128 + wm + i * 16 + quad * 4 + r;
#pragma unroll
      for (int j = 0; j < 4; ++j) {
        int o = ov[j];
        float val = acc[i][j][r] + bb[j];
        if (o < 384) {
          qk[(size_t)t * 768 + o] = f2bf(val * 0.17677669529663687f);
        } else if (o < 768) {
          qk[(size_t)t * 768 + o] = f2bf(val);
        } else {
          vb[(size_t)t * 384 + o - 768] = f2bf(val);
        }
      }
    }
  }
}

// ---------------------------------------------------------------------------
// Kernel 2: barrier-free attention. One wave per (window, head).
// Wave-private LDS: vL[49][40] + P[49][72] + tb[169 fp32]; no __syncthreads.
// ---------------------------------------------------------------------------
#define WSZ 5832   // per-wave LDS elems (16B-aligned stride)
#define VLB 0
#define PB  1960
#define TBB 5488
__global__ __launch_bounds__(256) void attn(
    const unsigned short* __restrict__ qk,
    const unsigned short* __restrict__ vb,
    const float* __restrict__ table,
    unsigned short* __restrict__ ob) {
  __shared__ unsigned short lds[4 * WSZ];
  const int lane = threadIdx.x & 63;
  const int wave = threadIdx.x >> 6, quad = lane >> 4, l16 = lane & 15;
  const int bwh = blockIdx.x * 4 + wave;  // 0..12287
  const int bw = bwh / 12, h = bwh - bw * 12;
  const int win = bw & 63, wy = win >> 3, wx = win & 7;
  unsigned short* my = lds + wave * WSZ;
  float* tbf = (float*)(my + TBB);

  bf16x8 zf;
#pragma unroll
  for (int i = 0; i < 8; ++i) zf[i] = (__bf16)0.0f;
  const floatx4 zz = {0.f, 0.f, 0.f, 0.f};

  // table slice for this head -> LDS
  for (int i = lane; i < 169; i += 64) tbf[i] = table[i * 12 + h];

  // stage v rows (and zero pad rows 49..63)
  const unsigned short* vbase = vb + (size_t)(bw * 49) * 384 + h * 32;
#pragma unroll
  for (int it = 0; it < 4; ++it) {
    int idx = it * 64 + lane;
    int row = idx >> 2, ch = idx & 3;
    if (idx < 196)
      *(bf16x8*)&my[VLB + row * 40 + ch * 8] =
          *(const bf16x8*)(vbase + (size_t)row * 384 + ch * 8);
    else
      *(bf16x8*)&my[VLB + row * 40 + ch * 8] = zf;
  }

  // q/k fragments straight from global
  const unsigned short* qbase = qk + (size_t)(bw * 49) * 768 + h * 32;
  bf16x8 aq[4], bk[4];
#pragma unroll
  for (int mt = 0; mt < 4; ++mt) {
    int m = mt * 16 + l16;
    aq[mt] = (m < 49) ? *(const bf16x8*)(qbase + (size_t)m * 768 + quad * 8) : zf;
    bk[mt] = (m < 49) ? *(const bf16x8*)(qbase + 384 + (size_t)m * 768 + quad * 8) : zf;
  }

  floatx4 s[4][4];
#pragma unroll
  for (int mt = 0; mt < 4; ++mt)
#pragma unroll
    for (int nt = 0; nt < 4; ++nt)
      s[mt][nt] = __builtin_amdgcn_mfma_f32_16x16x32_bf16(aq[mt], bk[nt], zz, 0, 0, 0);

  // column-side mask info
  int yj[4], xj[4], ccv[4];
#pragma unroll
  for (int nt = 0; nt < 4; ++nt) {
    int j = nt * 16 + l16;
    int y = (j * 37) >> 8, xx = j - y * 7;
    yj[nt] = y; xj[nt] = xx;
    ccv[nt] = reg3(wy * 7 + y) * 3 + reg3(wx * 7 + xx);
  }

  const float NEG = -1e30f;
#pragma unroll
  for (int mt = 0; mt < 4; ++mt) {
#pragma unroll
    for (int r = 0; r < 4; ++r) {
      int i = mt * 16 + quad * 4 + r;
      int yi = (i * 37) >> 8, xi = i - yi * 7;
      int rc = reg3(wy * 7 + yi) * 3 + reg3(wx * 7 + xi);
      bool rowok = (i < 49);
      float vals[4];
      float mx = NEG;
#pragma unroll
      for (int nt = 0; nt < 4; ++nt) {
        int j = nt * 16 + l16;
        float v = s[mt][nt][r];
        if (rowok && j < 49) {
          v += tbf[(yi - yj[nt] + 6) * 13 + (xi - xj[nt] + 6)];
          if (rc != ccv[nt]) v -= 100.0f;
        } else {
          v = NEG;
        }
        vals[nt] = v;
        mx = fmaxf(mx, v);
      }
#pragma unroll
      for (int off = 1; off < 16; off <<= 1)
        mx = fmaxf(mx, __shfl_xor(mx, off, 64));
      float sum = 0.f;
#pragma unroll
      for (int nt = 0; nt < 4; ++nt) {
        float e = __expf(vals[nt] - mx);
        vals[nt] = e;
        sum += e;
      }
#pragma unroll
      for (int off = 1; off < 16; off <<= 1) sum += __shfl_xor(sum, off, 64);
      float rinv = 1.f / sum;
      if (rowok) {
#pragma unroll
        for (int nt = 0; nt < 4; ++nt)
          my[PB + i * 72 + nt * 16 + l16] = f2bf(vals[nt] * rinv);
      }
    }
  }

  // PV: A = P (LDS), B = v (LDS, scalar-gathered transpose)
  floatx4 oacc[4][2];
#pragma unroll
  for (int mt = 0; mt < 4; ++mt) { oacc[mt][0] = zz; oacc[mt][1] = zz; }
#pragma unroll
  for (int ks2 = 0; ks2 < 2; ++ks2) {
    bf16x8 bv[2];
#pragma unroll
    for (int nt = 0; nt < 2; ++nt) {
#pragma unroll
      for (int jj = 0; jj < 8; ++jj)
        bv[nt][jj] = __builtin_bit_cast(
            __bf16, my[VLB + (ks2 * 32 + quad * 8 + jj) * 40 + nt * 16 + l16]);
    }
#pragma unroll
    for (int mt = 0; mt < 4; ++mt) {
      int m = mt * 16 + l16;
      bf16x8 ap = (m < 49)
          ? *(const bf16x8*)&my[PB + m * 72 + ks2 * 32 + quad * 8] : zf;
#pragma unroll
      for (int nt = 0; nt < 2; ++nt)
        oacc[mt][nt] = __builtin_amdgcn_mfma_f32_16x16x32_bf16(ap, bv[nt], oacc[mt][nt], 0, 0, 0);
    }
  }

  unsigned short* obase = ob + (size_t)(bw * 49) * 384 + h * 32;
#pragma unroll
  for (int mt = 0; mt < 4; ++mt) {
#pragma unroll
    for (int r = 0; r < 4; ++r) {
      int i = mt * 16 + quad * 4 + r;
      if (i < 49) {
#pragma unroll
        for (int nt = 0; nt < 2; ++nt)
          obase[(size_t)i * 384 + nt * 16 + l16] = f2bf(oacc[mt][nt][r]);
      }
    }
  }
}

// ---------------------------------------------------------------------------
// Kernel 3: proj GEMM (bf16 in, fp32 out) + inverse-shift scatter + bias.
// ---------------------------------------------------------------------------
__global__ __launch_bounds__(256, 2) void proj_gemm(
    const unsigned short* __restrict__ a,
    const unsigned short* __restrict__ w,
    const float* __restrict__ bias,
    float* __restrict__ out) {
  __shared__ unsigned short As[128 * 32];
  __shared__ unsigned short Bs[128 * 32];
  const int tid = threadIdx.x;
  const int wave = tid >> 6, lane = tid & 63, quad = lane >> 4, l16 = lane & 15;
  const int tm = blockIdx.x;  // 0..391
  const int tn = blockIdx.y;  // 0..2

  const unsigned short* asrc[2];
  const unsigned short* bsrc[2];
#pragma unroll
  for (int s = 0; s < 2; ++s) {
    int row = wave * 32 + s * 16 + (lane >> 2);
    asrc[s] = a + (size_t)(tm * 128 + row) * 384 + (lane & 3) * 8;
    bsrc[s] = w + (size_t)(tn * 128 + row) * 384 + (lane & 3) * 8;
  }

  const int wm = (wave & 1) * 64, wn = (wave >> 1) * 64;
  const floatx4 zz = {0.f, 0.f, 0.f, 0.f};
  floatx4 acc[4][4];
#pragma unroll
  for (int i = 0; i < 4; ++i)
#pragma unroll
    for (int j = 0; j < 4; ++j) acc[i][j] = zz;

  for (int kk = 0; kk < 12; ++kk) {
    if (kk) __syncthreads();
#pragma unroll
    for (int s = 0; s < 2; ++s) {
      gload_lds16(asrc[s] + kk * 32, &As[(wave * 32 + s * 16) * 32]);
      gload_lds16(bsrc[s] + kk * 32, &Bs[(wave * 32 + s * 16) * 32]);
    }
    __syncthreads();
    bf16x8 af[4], bfg[4];
#pragma unroll
    for (int i = 0; i < 4; ++i) {
      af[i]  = *(const bf16x8*)&As[(wm + i * 16 + l16) * 32 + quad * 8];
      bfg[i] = *(const bf16x8*)&Bs[(wn + i * 16 + l16) * 32 + quad * 8];
    }
#pragma unroll
    for (int i = 0; i < 4; ++i)
#pragma unroll
      for (int j = 0; j < 4; ++j)
        acc[i][j] = __builtin_amdgcn_mfma_f32_16x16x32_bf16(af[i], bfg[j], acc[i][j], 0, 0, 0);
  }

  float bb[4];
  int ov[4];
#pragma unroll
  for (int j = 0; j < 4; ++j) {
    ov[j] = tn * 128 + wn + j * 16 + l16;
    bb[j] = bias[ov[j]];
  }

#pragma unroll
  for (int i = 0; i < 4; ++i) {
#pragma unroll
    for (int r = 0; r < 4; ++r) {
      int t = tm * 128 + wm + i * 16 + quad * 4 + r;
      int bw = t / 49;
      int pos = t - bw * 49;
      int b = bw >> 6, win = bw & 63, wy = win >> 3, wx = win & 7;
      int py = pos / 7, px = pos - py * 7;
      int hh = wy * 7 + py + 3; if (hh >= 56) hh -= 56;
      int wc = wx * 7 + px + 3; if (wc >= 56) wc -= 56;
      size_t base = (size_t)((b * 56 + hh) * 56 + wc) * 384;
#pragma unroll
      for (int j = 0; j < 4; ++j)
        out[base + ov[j]] = acc[i][j][r] + bb[j];
    }
  }
}

// ===========================================================================
// Fallback path (round-4, passing at 858 us) for small workspace.
// ===========================================================================
#define XW 0
#define QO 19208
#define KO 21768
#define VT 24328
#define PO 19208
#define LDSN 26632

__global__ __launch_bounds__(256) void swin_fused(
    const float* __restrict__ x, const float* __restrict__ w,
    const float* __restrict__ qkvb, const float* __restrict__ table,
    float* __restrict__ out) {
  __shared__ unsigned short lds[LDSN];
  const int tid = threadIdx.x;
  const int wave = tid >> 6, lane = tid & 63, quad = lane >> 4, l16 = lane & 15;
  const int bw = blockIdx.x;
  const int b = bw >> 6, win = bw & 63, wy = win >> 3, wx = win & 7;

  bf16x8 zf;
#pragma unroll
  for (int i = 0; i < 8; ++i) zf[i] = (__bf16)0.0f;
  const floatx4 zz = {0.f, 0.f, 0.f, 0.f};

  for (int c = tid; c < 2352; c += 256) {
    int r = c / 48, c8 = c - r * 48;
    int py = (r * 37) >> 8, px = r - py * 7;
    int hh = wy * 7 + py + 3; if (hh >= 56) hh -= 56;
    int wc = wx * 7 + px + 3; if (wc >= 56) wc -= 56;
    *(bf16x8*)&lds[XW + r * 392 + c8 * 8] =
        cvt8(x + (size_t)((b * 56 + hh) * 56 + wc) * 384 + c8 * 8);
  }
  __syncthreads();

  int yj[4], xj[4], ccv[4];
#pragma unroll
  for (int nt = 0; nt < 4; ++nt) {
    int j = nt * 16 + l16;
    int y = (j * 37) >> 8, xx = j - y * 7;
    yj[nt] = y; xj[nt] = xx;
    ccv[nt] = reg3(wy * 7 + y) * 3 + reg3(wx * 7 + xx);
  }

  for (int g = 0; g < 3; ++g) {
    const int hme = g * 4 + wave;
    const float* bp[6];
    int wrowv[6];
#pragma unroll
    for (int nt = 0; nt < 6; ++nt) {
      int which = nt >> 1;
      int n32 = (nt & 1) * 16 + l16;
      int wrow = which * 384 + hme * 32 + n32;
      wrowv[nt] = wrow;
      bp[nt] = w + (size_t)wrow * 384 + quad * 8;
    }

    floatx4 acc[4][6];
#pragma unroll
    for (int mt = 0; mt < 4; ++mt)
#pragma unroll
      for (int nt = 0; nt < 6; ++nt) acc[mt][nt] = zz;

    for (int ks = 0; ks < 12; ++ks) {
      bf16x8 af[4];
#pragma unroll
      for (int mt = 0; mt < 4; ++mt) {
        int am = mt * 16 + l16;
        af[mt] = (am < 49) ? *(const bf16x8*)&lds[XW + am * 392 + ks * 32 + quad * 8] : zf;
      }
#pragma unroll
      for (int nt = 0; nt < 6; ++nt) {
        bf16x8 bfr = cvt8(bp[nt] + ks * 32);
#pragma unroll
        for (int mt = 0; mt < 4; ++mt)
          acc[mt][nt] = __builtin_amdgcn_mfma_f32_16x16x32_bf16(af[mt], bfr, acc[mt][nt], 0, 0, 0);
      }
    }

    for (int hh2 = 0; hh2 < 4; ++hh2) {
      const int h = g * 4 + hh2;
      __syncthreads();
      if (wave == hh2) {
        float bb[6];
#pragma unroll
        for (int nt = 0; nt < 6; ++nt) bb[nt] = qkvb[wrowv[nt]];
#pragma unroll
        for (int mt = 0; mt < 4; ++mt) {
#pragma unroll
          for (int r = 0; r < 4; ++r) {
            int token = mt * 16 + quad * 4 + r;
#pragma unroll
            for (int nt = 0; nt < 6; ++nt) {
              float val = acc[mt][nt][r] + bb[nt];
              int n32 = (nt & 1) * 16 + l16;
              if (nt < 2)
                lds[QO + token * 40 + n32] = f2bf(val * 0.17677669529663687f);
              else if (nt < 4)
                lds[KO + token * 40 + n32] = f2bf(val);
              else
                lds[VT + n32 * 72 + token] = f2bf(val);
            }
          }
        }
      }
      __syncthreads();

      bf16x8 aq = *(const bf16x8*)&lds[QO + (wave * 16 + l16) * 40 + quad * 8];
      bf16x8 bk[4];
#pragma unroll
      for (int nt = 0; nt < 4; ++nt)
        bk[nt] = *(const bf16x8*)&lds[KO + (nt * 16 + l16) * 40 + quad * 8];
      bf16x8 bv[2][2];
#pragma unroll
      for (int nt = 0; nt < 2; ++nt)
#pragma unroll
        for (int ks = 0; ks < 2; ++ks)
          bv[nt][ks] = *(const bf16x8*)&lds[VT + (nt * 16 + l16) * 72 + ks * 32 + quad * 8];
      __syncthreads();

      floatx4 s4[4];
#pragma unroll
      for (int nt = 0; nt < 4; ++nt)
        s4[nt] = __builtin_amdgcn_mfma_f32_16x16x32_bf16(aq, bk[nt], zz, 0, 0, 0);

      const float NEG = -1e30f;
#pragma unroll
      for (int r = 0; r < 4; ++r) {
        int i = wave * 16 + quad * 4 + r;
        int yi = (i * 37) >> 8, xi = i - yi * 7;
        int rc = reg3(wy * 7 + yi) * 3 + reg3(wx * 7 + xi);
        bool rowok = (i < 49);
        float vals[4];
        float mx = NEG;
#pragma unroll
        for (int nt = 0; nt < 4; ++nt) {
          int j = nt * 16 + l16;
          float v = s4[nt][r];
          if (rowok && j < 49) {
            v += table[((yi - yj[nt] + 6) * 13 + (xi - xj[nt] + 6)) * 12 + h];
            if (rc != ccv[nt]) v -= 100.0f;
          } else {
            v = NEG;
          }
          vals[nt] = v;
          mx = fmaxf(mx, v);
        }
#pragma unroll
        for (int off = 1; off < 16; off <<= 1)
          mx = fmaxf(mx, __shfl_xor(mx, off, 64));
        float sum = 0.f;
#pragma unroll
        for (int nt = 0; nt < 4; ++nt) {
          float e = __expf(vals[nt] - mx);
          vals[nt] = e;
          sum += e;
        }
#pragma unroll
        for (int off = 1; off < 16; off <<= 1) sum += __shfl_xor(sum, off, 64);
        float rinv = 1.f / sum;
#pragma unroll
        for (int nt = 0; nt < 4; ++nt)
          lds[PO + i * 72 + nt * 16 + l16] = f2bf(vals[nt] * rinv);
      }
      __syncthreads();

      bf16x8 ap[2];
#pragma unroll
      for (int ks = 0; ks < 2; ++ks)
        ap[ks] = *(const bf16x8*)&lds[PO + (wave * 16 + l16) * 72 + ks * 32 + quad * 8];
      floatx4 o2[2] = {zz, zz};
#pragma unroll
      for (int ks = 0; ks < 2; ++ks)
#pragma unroll
        for (int nt = 0; nt < 2; ++nt)
          o2[nt] = __builtin_amdgcn_mfma_f32_16x16x32_bf16(ap[ks], bv[nt][ks], o2[nt], 0, 0, 0);

#pragma unroll
      for (int r = 0; r < 4; ++r) {
        int i = wave * 16 + quad * 4 + r;
        if (i < 49) {
          int py = (i * 37) >> 8, px = i - py * 7;
          int hh = wy * 7 + py + 3; if (hh >= 56) hh -= 56;
          int wc = wx * 7 + px + 3; if (wc >= 56) wc -= 56;
          size_t base = (size_t)((b * 56 + hh) * 56 + wc) * 384 + h * 32;
#pragma unroll
          for (int nt = 0; nt < 2; ++nt)
            out[base + nt * 16 + l16] = o2[nt][r];
        }
      }
    }
  }
}

__global__ __launch_bounds__(256) void proj_inplace(
    float* __restrict__ out, const float* __restrict__ w,
    const float* __restrict__ pb) {
  __shared__ unsigned short A[64 * 392];
  const int tid = threadIdx.x;
  const int wave = tid >> 6, lane = tid & 63, quad = lane >> 4, l16 = lane & 15;
  const int tm = blockIdx.x;

  for (int c = tid; c < 3072; c += 256) {
    int r = c / 48, c8 = c - r * 48;
    *(bf16x8*)&A[r * 392 + c8 * 8] = cvt8(out + (size_t)(tm * 64 + r) * 384 + c8 * 8);
  }
  __syncthreads();

  const float* bp[6];
#pragma unroll
  for (int nt = 0; nt < 6; ++nt)
    bp[nt] = w + (size_t)(wave * 96 + nt * 16 + l16) * 384 + quad * 8;

  const floatx4 zz = {0.f, 0.f, 0.f, 0.f};
  floatx4 acc[4][6];
#pragma unroll
  for (int mt = 0; mt < 4; ++mt)
#pragma unroll
    for (int nt = 0; nt < 6; ++nt) acc[mt][nt] = zz;

  for (int ks = 0; ks < 12; ++ks) {
    bf16x8 af[4];
#pragma unroll
    for (int mt = 0; mt < 4; ++mt)
      af[mt] = *(const bf16x8*)&A[(mt * 16 + l16) * 392 + ks * 32 + quad * 8];
#pragma unroll
    for (int nt = 0; nt < 6; ++nt) {
      bf16x8 bfr = cvt8(bp[nt] + ks * 32);
#pragma unroll
      for (int mt = 0; mt < 4; ++mt)
        acc[mt][nt] = __builtin_amdgcn_mfma_f32_16x16x32_bf16(af[mt], bfr, acc[mt][nt], 0, 0, 0);
    }
  }

#pragma unroll
  for (int mt = 0; mt < 4; ++mt) {
#pragma unroll
    for (int r = 0; r < 4; ++r) {
      int t = tm * 64 + mt * 16 + quad * 4 + r;
#pragma unroll
      for (int nt = 0; nt < 6; ++nt) {
        int col = wave * 96 + nt * 16 + l16;
        out[(size_t)t * 384 + col] = acc[mt][nt][r] + pb[col];
      }
    }
  }
}

extern "C" void kernel_launch(void* const* d_in, const int* in_sizes, int n_in,
                              void* d_out, int out_size, void* d_ws, size_t ws_size,
                              hipStream_t stream) {
  const float* x      = (const float*)d_in[0];
  const float* qkv_w  = (const float*)d_in[1];
  const float* qkv_b  = (const float*)d_in[2];
  const float* proj_w = (const float*)d_in[3];
  const float* proj_b = (const float*)d_in[4];
  const float* table  = (const float*)d_in[5];
  float* out = (float*)d_out;

  const size_t NEED = (size_t)(NX + NQW + NPW + NX + NX) * 2;  // 116,785,152 B
  if (ws_size >= NEED) {
    unsigned short* xb  = (unsigned short*)d_ws;
    unsigned short* wqb = xb + NX;
    unsigned short* wpb = wqb + NQW;
    unsigned short* vb  = wpb + NPW;
    unsigned short* ob  = vb + NX;
    unsigned short* qkb = (unsigned short*)d_out;  // q+k scratch fills d_out exactly

    cvt_all<<<9696, 256, 0, stream>>>(x, qkv_w, proj_w, xb, wqb, wpb);
    dim3 g1(392, 9);
    qkv_gemm<<<g1, 256, 0, stream>>>(xb, wqb, qkv_b, qkb, vb);
    attn<<<3072, 256, 0, stream>>>(qkb, vb, table, ob);
    dim3 g3(392, 3);
    proj_gemm<<<g3, 256, 0, stream>>>(ob, wpb, proj_b, out);
  } else {
    swin_fused<<<1024, 256, 0, stream>>>(x, qkv_w, qkv_b, table, out);
    proj_inplace<<<784, 256, 0, stream>>>(out, proj_w, proj_b);
  }
}